// Round 3
// baseline (298.380 us; speedup 1.0000x reference)
//
#include <hip/hip_runtime.h>
#include <math.h>

#define H 1024
#define W 1024
#define OH 1016
#define OW 1016
#define BH 8           // output rows per band
#define NB (OH/BH)     // 127 bands (exact: 8*127 = 1016)
#define EPS 1e-6f
#define INV25 (1.0f/25.0f)

// Pure register-streaming kernel: no LDS, no barriers.
// Thread t owns output cols j0=4t..4t+3 of one 8-row band of one image.
// Register state:
//   cs_x[12], cs_y[12] : 5-row column sums of x,y at input cols j0..j0+11
//   rdx[5][8], rdy[5][8]: ring of last 5 dx,dy rows at cols j0..j0+7 (static idx)
//   cp1..cp3[8]        : 5-row column sums of dx*dy, dx*dx, dy*dy

__device__ __forceinline__ void load12(const float* p, float v[12]) {
    float4 a = *reinterpret_cast<const float4*>(p);
    float4 b = *reinterpret_cast<const float4*>(p + 4);
    float4 c = *reinterpret_cast<const float4*>(p + 8);
    v[0]=a.x; v[1]=a.y; v[2]=a.z;  v[3]=a.w;
    v[4]=b.x; v[5]=b.y; v[6]=b.z;  v[7]=b.w;
    v[8]=c.x; v[9]=c.y; v[10]=c.z; v[11]=c.w;
}

__global__ __launch_bounds__(256, 2)
void yiq_gngc_stream(const float* __restrict__ x, const float* __restrict__ y,
                     float* __restrict__ out, long long Nper) {
    const int t = threadIdx.x;
    if (t >= OW / 4) return;                 // 254 active threads
    const int j0 = t * 4;
    const int i0 = blockIdx.x * BH;
    const int b  = blockIdx.y;
    const float* xb = x + (size_t)b * (H * W) + j0;
    const float* yb = y + (size_t)b * (H * W) + j0;

    float cs_x[12], cs_y[12];
    float rdx[5][8], rdy[5][8];
    float cp1[8], cp2[8], cp3[8];
    #pragma unroll
    for (int k = 0; k < 12; ++k) { cs_x[k] = 0.f; cs_y[k] = 0.f; }
    #pragma unroll
    for (int k = 0; k < 8; ++k) {
        cp1[k] = 0.f; cp2[k] = 0.f; cp3[k] = 0.f;
        rdx[4][k] = 0.f; rdy[4][k] = 0.f;    // slot 4 read-before-write at it=0
    }

    // ---- initial column sums over input rows i0..i0+4 ----
    #pragma unroll
    for (int r = 0; r < 5; ++r) {
        float vx[12], vy[12];
        load12(xb + (size_t)(i0 + r) * W, vx);
        load12(yb + (size_t)(i0 + r) * W, vy);
        #pragma unroll
        for (int k = 0; k < 12; ++k) { cs_x[k] += vx[k]; cs_y[k] += vy[k]; }
    }

    // ---- prime 4 dx/dy rows: rows i0+pr, pr=0..3 ----
    #pragma unroll
    for (int pr = 0; pr < 4; ++pr) {
        float xc[12], yc[12];
        load12(xb + (size_t)(i0 + pr + 2) * W, xc);   // center row
        load12(yb + (size_t)(i0 + pr + 2) * W, yc);
        #pragma unroll
        for (int k = 0; k < 8; ++k) {
            float sx = cs_x[k] + cs_x[k+1] + cs_x[k+2] + cs_x[k+3] + cs_x[k+4];
            float sy = cs_y[k] + cs_y[k+1] + cs_y[k+2] + cs_y[k+3] + cs_y[k+4];
            float dx = xc[k + 2] - sx * INV25;
            float dy = yc[k + 2] - sy * INV25;
            rdx[pr][k] = dx; rdy[pr][k] = dy;
            cp1[k] += dx * dy; cp2[k] += dx * dx; cp3[k] += dy * dy;
        }
        // slide colsums: add row i0+pr+5, drop row i0+pr (reload; L1/L2 warm)
        {
            float nx[12], ox[12];
            load12(xb + (size_t)(i0 + pr + 5) * W, nx);
            load12(xb + (size_t)(i0 + pr) * W, ox);
            #pragma unroll
            for (int k = 0; k < 12; ++k) cs_x[k] += nx[k] - ox[k];
        }
        {
            float ny[12], oy[12];
            load12(yb + (size_t)(i0 + pr + 5) * W, ny);
            load12(yb + (size_t)(i0 + pr) * W, oy);
            #pragma unroll
            for (int k = 0; k < 12; ++k) cs_y[k] += ny[k] - oy[k];
        }
    }

    // ---- main loop: output rows i = i0+it, it=0..7 ----
    float* ob = out + (size_t)b * ((size_t)OH * OW) + j0;
    #pragma unroll
    for (int it = 0; it < BH; ++it) {
        const int i = i0 + it;
        // cs currently = sum of input rows i+4..i+8 -> new dx/dy row i+4
        float xc[12], yc[12];
        load12(xb + (size_t)(i + 6) * W, xc);          // center row for dx row i+4
        load12(yb + (size_t)(i + 6) * W, yc);
        const int s = (it + 4) % 5;                    // slot of dropped row i-1 == new row i+4
        #pragma unroll
        for (int k = 0; k < 8; ++k) {
            float sx = cs_x[k] + cs_x[k+1] + cs_x[k+2] + cs_x[k+3] + cs_x[k+4];
            float sy = cs_y[k] + cs_y[k+1] + cs_y[k+2] + cs_y[k+3] + cs_y[k+4];
            float dx = xc[k + 2] - sx * INV25;
            float dy = yc[k + 2] - sy * INV25;
            float odx = rdx[s][k], ody = rdy[s][k];
            cp1[k] += dx * dy - odx * ody;
            cp2[k] += dx * dx - odx * odx;
            cp3[k] += dy * dy - ody * ody;
            rdx[s][k] = dx; rdy[s][k] = dy;
        }
        // finalize output row i, cols j0..j0+3
        float co[4], vv[4], cc[4];
        #pragma unroll
        for (int q = 0; q < 4; ++q) {
            float c_ = (cp1[q] + cp1[q+1] + cp1[q+2] + cp1[q+3] + cp1[q+4]) * INV25;
            float vx = (cp2[q] + cp2[q+1] + cp2[q+2] + cp2[q+3] + cp2[q+4]) * INV25;
            float vy = (cp3[q] + cp3[q+1] + cp3[q+2] + cp3[q+3] + cp3[q+4]) * INV25;
            float v  = sqrtf(vx * vy);
            bool low = v < EPS;
            float cv = low ? 0.f : c_;
            float vs = low ? EPS : v;
            float r_ = cv / vs;
            r_ = r_ < 0.f ? 0.f : (r_ > 1.f ? 1.f : r_);
            co[q] = r_; vv[q] = vs; cc[q] = cv;
        }
        float* o = ob + (size_t)i * OW;
        *reinterpret_cast<float4*>(o)            = make_float4(co[0], co[1], co[2], co[3]);
        *reinterpret_cast<float4*>(o + Nper)     = make_float4(vv[0], vv[1], vv[2], vv[3]);
        *reinterpret_cast<float4*>(o + 2 * Nper) = make_float4(cc[0], cc[1], cc[2], cc[3]);
        // slide colsums for next iteration: add row i+9, drop row i+4
        if (it < BH - 1) {
            {
                float nx[12], ox[12];
                load12(xb + (size_t)(i + 9) * W, nx);
                load12(xb + (size_t)(i + 4) * W, ox);
                #pragma unroll
                for (int k = 0; k < 12; ++k) cs_x[k] += nx[k] - ox[k];
            }
            {
                float ny[12], oy[12];
                load12(yb + (size_t)(i + 9) * W, ny);
                load12(yb + (size_t)(i + 4) * W, oy);
                #pragma unroll
                for (int k = 0; k < 12; ++k) cs_y[k] += ny[k] - oy[k];
            }
        }
    }
}

extern "C" void kernel_launch(void* const* d_in, const int* in_sizes, int n_in,
                              void* d_out, int out_size, void* d_ws, size_t ws_size,
                              hipStream_t stream) {
    const float* x = (const float*)d_in[0];
    const float* y = (const float*)d_in[1];
    // mask (d_in[2]) unused by the reference's channels==1 path
    float* out = (float*)d_out;
    const int B = in_sizes[0] / (H * W);
    const long long Nper = (long long)out_size / 3;   // elements per output array
    dim3 grid(NB, B);
    yiq_gngc_stream<<<grid, dim3(256), 0, stream>>>(x, y, out, Nper);
}

// Round 4
// 73.559 us; speedup vs baseline: 4.0563x; 4.0563x over previous
//
#include <hip/hip_runtime.h>
#include <math.h>

#define H 1024
#define W 1024
#define OH 1016
#define OW 1016
#define BH 16          // output rows per band
#define NBANDS 64      // ceil(1016/16); last band has 8 valid rows
#define EPS 1e-6f
#define INV25 (1.0f/25.0f)

// Register-sliding band kernel with a 5-row LDS ring for dx/dy.
// Thread t owns output cols j0=4t..4t+3 (t clamped to 253; full width 1016).
// Register state: cs_x/cs_y[12] (5-row column sums of inputs),
//                 cp1..cp3[8] (5-row column sums of dx*dy, dx^2, dy^2).
// LDS ring[5][2][1024]: last 5 dx (a=0) / dy (a=1) rows; used only to
// retrieve the row dropping out of the product window (subtract).

__device__ __forceinline__ float4 ld4(const float* p){ return *reinterpret_cast<const float4*>(p); }
__device__ __forceinline__ void st4(float* p, float4 v){ *reinterpret_cast<float4*>(p) = v; }

__device__ __forceinline__ void load12(const float* p, float v[12]) {
    float4 a = ld4(p), b = ld4(p + 4), c = ld4(p + 8);
    v[0]=a.x; v[1]=a.y; v[2]=a.z;  v[3]=a.w;
    v[4]=b.x; v[5]=b.y; v[6]=b.z;  v[7]=b.w;
    v[8]=c.x; v[9]=c.y; v[10]=c.z; v[11]=c.w;
}

__global__ __launch_bounds__(256, 3)
void yiq_gngc_band(const float* __restrict__ x, const float* __restrict__ y,
                   float* __restrict__ out, long long Nper)
{
    __shared__ __align__(16) float ring[5][2][1024];
    int tr = (int)threadIdx.x; if (tr > 253) tr = 253;   // lanes 254/255 duplicate t=253 (benign)
    const bool last = (tr == 253);
    const int j0 = tr * 4;
    const int i0 = blockIdx.x * BH;
    const int b  = blockIdx.y;
    const float* xb = x + (size_t)b * (H * W) + j0;
    const float* yb = y + (size_t)b * (H * W) + j0;

    float cs_x[12], cs_y[12];
    float cp1[8], cp2[8], cp3[8];
    #pragma unroll
    for (int k = 0; k < 12; ++k) { cs_x[k] = 0.f; cs_y[k] = 0.f; }
    #pragma unroll
    for (int k = 0; k < 8; ++k) { cp1[k] = 0.f; cp2[k] = 0.f; cp3[k] = 0.f; }

    // ---- initial input column sums over rows i0..i0+4 ----
    #pragma unroll
    for (int r = 0; r < 5; ++r) {
        float vx[12], vy[12];
        load12(xb + (size_t)(i0 + r) * W, vx);
        load12(yb + (size_t)(i0 + r) * W, vy);
        #pragma unroll
        for (int k = 0; k < 12; ++k) { cs_x[k] += vx[k]; cs_y[k] += vy[k]; }
    }

    // ---- zero ring slot 4 (read at it=0 as the "row -1" to subtract) ----
    {
        float4 z = make_float4(0.f, 0.f, 0.f, 0.f);
        st4(&ring[4][0][j0], z); st4(&ring[4][1][j0], z);
        if (last) { st4(&ring[4][0][j0 + 4], z); st4(&ring[4][1][j0 + 4], z); }
    }

    // ---- prime dx/dy rows i0..i0+3 into ring slots 0..3; accumulate cp ----
    #pragma unroll
    for (int pr = 0; pr < 4; ++pr) {
        float xc[12], yc[12];
        load12(xb + (size_t)(i0 + pr + 2) * W, xc);   // center row
        load12(yb + (size_t)(i0 + pr + 2) * W, yc);
        float dxn[8], dyn[8];
        #pragma unroll
        for (int k = 0; k < 8; ++k) {
            float sx = cs_x[k] + cs_x[k+1] + cs_x[k+2] + cs_x[k+3] + cs_x[k+4];
            float sy = cs_y[k] + cs_y[k+1] + cs_y[k+2] + cs_y[k+3] + cs_y[k+4];
            dxn[k] = xc[k + 2] - sx * INV25;
            dyn[k] = yc[k + 2] - sy * INV25;
            cp1[k] += dxn[k] * dyn[k];
            cp2[k] += dxn[k] * dxn[k];
            cp3[k] += dyn[k] * dyn[k];
        }
        st4(&ring[pr][0][j0], make_float4(dxn[0], dxn[1], dxn[2], dxn[3]));
        st4(&ring[pr][1][j0], make_float4(dyn[0], dyn[1], dyn[2], dyn[3]));
        if (last) {
            st4(&ring[pr][0][j0 + 4], make_float4(dxn[4], dxn[5], dxn[6], dxn[7]));
            st4(&ring[pr][1][j0 + 4], make_float4(dyn[4], dyn[5], dyn[6], dyn[7]));
        }
        // slide cs: add row i0+pr+5, drop row i0+pr (all indices <= 1016, in-bounds)
        float nx[12], ox[12], ny[12], oy[12];
        load12(xb + (size_t)(i0 + pr + 5) * W, nx);
        load12(xb + (size_t)(i0 + pr) * W, ox);
        load12(yb + (size_t)(i0 + pr + 5) * W, ny);
        load12(yb + (size_t)(i0 + pr) * W, oy);
        #pragma unroll
        for (int k = 0; k < 12; ++k) { cs_x[k] += nx[k] - ox[k]; cs_y[k] += ny[k] - oy[k]; }
    }
    __syncthreads();

    float* ob = out + (size_t)b * ((size_t)OH * OW) + j0;
    int s = 4;   // ring slot of the row leaving the window (== slot of the new row)

    #pragma unroll 4
    for (int it = 0; it < BH; ++it) {
        const int i = i0 + it;
        if (i >= OH) break;                         // block-uniform (tail band)

        // center row for new dx/dy row i+4
        float xc[12], yc[12];
        load12(xb + (size_t)(i + 6) * W, xc);
        load12(yb + (size_t)(i + 6) * W, yc);

        // read old dx/dy (row i-1) from slot s BEFORE overwriting it
        float4 oxa = ld4(&ring[s][0][j0]);
        float4 oxb = ld4(&ring[s][0][j0 + 4]);
        float4 oya = ld4(&ring[s][1][j0]);
        float4 oyb = ld4(&ring[s][1][j0 + 4]);
        __syncthreads();                            // all reads of slot s done

        // new dx/dy row i+4 (8 halo cols, all in registers)
        float dxn[8], dyn[8];
        #pragma unroll
        for (int k = 0; k < 8; ++k) {
            float sx = cs_x[k] + cs_x[k+1] + cs_x[k+2] + cs_x[k+3] + cs_x[k+4];
            float sy = cs_y[k] + cs_y[k+1] + cs_y[k+2] + cs_y[k+3] + cs_y[k+4];
            dxn[k] = xc[k + 2] - sx * INV25;
            dyn[k] = yc[k + 2] - sy * INV25;
        }
        st4(&ring[s][0][j0], make_float4(dxn[0], dxn[1], dxn[2], dxn[3]));
        st4(&ring[s][1][j0], make_float4(dyn[0], dyn[1], dyn[2], dyn[3]));
        if (last) {
            st4(&ring[s][0][j0 + 4], make_float4(dxn[4], dxn[5], dxn[6], dxn[7]));
            st4(&ring[s][1][j0 + 4], make_float4(dyn[4], dyn[5], dyn[6], dyn[7]));
        }

        // slide product column sums: + new row, - old row
        float odx[8] = {oxa.x, oxa.y, oxa.z, oxa.w, oxb.x, oxb.y, oxb.z, oxb.w};
        float ody[8] = {oya.x, oya.y, oya.z, oya.w, oyb.x, oyb.y, oyb.z, oyb.w};
        #pragma unroll
        for (int k = 0; k < 8; ++k) {
            cp1[k] += dxn[k] * dyn[k] - odx[k] * ody[k];
            cp2[k] += dxn[k] * dxn[k] - odx[k] * odx[k];
            cp3[k] += dyn[k] * dyn[k] - ody[k] * ody[k];
        }

        // finalize output row i, cols j0..j0+3
        float co[4], vv[4], cc[4];
        #pragma unroll
        for (int q = 0; q < 4; ++q) {
            float c_ = (cp1[q] + cp1[q+1] + cp1[q+2] + cp1[q+3] + cp1[q+4]) * INV25;
            float vx = (cp2[q] + cp2[q+1] + cp2[q+2] + cp2[q+3] + cp2[q+4]) * INV25;
            float vy = (cp3[q] + cp3[q+1] + cp3[q+2] + cp3[q+3] + cp3[q+4]) * INV25;
            float v  = sqrtf(vx * vy);
            bool lo  = v < EPS;
            float cv = lo ? 0.f : c_;
            float vs = lo ? EPS : v;
            float r_ = cv / vs;
            r_ = r_ < 0.f ? 0.f : (r_ > 1.f ? 1.f : r_);
            co[q] = r_; vv[q] = vs; cc[q] = cv;
        }
        float* o = ob + (size_t)i * OW;
        st4(o,            make_float4(co[0], co[1], co[2], co[3]));
        st4(o + Nper,     make_float4(vv[0], vv[1], vv[2], vv[3]));
        st4(o + 2 * Nper, make_float4(cc[0], cc[1], cc[2], cc[3]));

        // slide input column sums for next row: add row i+9, drop row i+4
        if (it < BH - 1) {
            int ra = i + 9; if (ra > H - 1) ra = H - 1;   // tail-band clamp (result unused)
            float nx[12], oxr[12], ny[12], oyr[12];
            load12(xb + (size_t)ra * W, nx);
            load12(xb + (size_t)(i + 4) * W, oxr);
            load12(yb + (size_t)ra * W, ny);
            load12(yb + (size_t)(i + 4) * W, oyr);
            #pragma unroll
            for (int k = 0; k < 12; ++k) { cs_x[k] += nx[k] - oxr[k]; cs_y[k] += ny[k] - oyr[k]; }
        }
        s = (s == 4) ? 0 : s + 1;
    }
}

extern "C" void kernel_launch(void* const* d_in, const int* in_sizes, int n_in,
                              void* d_out, int out_size, void* d_ws, size_t ws_size,
                              hipStream_t stream) {
    const float* x = (const float*)d_in[0];
    const float* y = (const float*)d_in[1];
    // mask (d_in[2]) unused by the reference's channels==1 path
    float* out = (float*)d_out;
    const int B = in_sizes[0] / (H * W);
    const long long Nper = (long long)out_size / 3;   // elements per output array
    dim3 grid(NBANDS, B);
    yiq_gngc_band<<<grid, dim3(256), 0, stream>>>(x, y, out, Nper);
}